// Round 2
// baseline (1008.429 us; speedup 1.0000x reference)
//
#include <hip/hip_runtime.h>
#include <math.h>

// Problem constants
#define B_ 4
#define L_ 1024
#define N_ 2048
#define VDIM_ 512
#define LDIM_ 768
#define HID_ 512
#define H_ 8
#define HD_ 64
#define SCALE_ 0.125f

// ---------------------------------------------------------------------------
// Generic GEMM: C[M,Nc] = A[M,K] @ W[Nc,K]^T (+ bias[n] if bias != nullptr)
// Requires M%64==0, Nc%64==0, K%16==0 (true for all three calls).
// 64x64 tile, BK=16, 256 threads, 4x4 micro-tile per thread.
// ---------------------------------------------------------------------------
__global__ __launch_bounds__(256)
void gemm_nt(const float* __restrict__ A, const float* __restrict__ W,
             const float* __restrict__ bias, float* __restrict__ C,
             int M, int Nc, int K)
{
    __shared__ float As[16][68];   // [k][m], stride 68 keeps f4 reads aligned
    __shared__ float Bs[16][68];   // [k][n]

    const int t  = threadIdx.x;
    const int n0 = blockIdx.x * 64;
    const int m0 = blockIdx.y * 64;
    const int tx = t & 15;         // col group (4 cols)
    const int ty = t >> 4;         // row group (4 rows)
    const int lr = t >> 2;         // 0..63: row index for tile loads
    const int kq = (t & 3) * 4;    // 0,4,8,12: k offset for tile loads

    float acc[4][4] = {{0.f,0.f,0.f,0.f},{0.f,0.f,0.f,0.f},
                       {0.f,0.f,0.f,0.f},{0.f,0.f,0.f,0.f}};

    const float* Arow = A + (size_t)(m0 + lr) * K + kq;
    const float* Wrow = W + (size_t)(n0 + lr) * K + kq;

    for (int kt = 0; kt < K; kt += 16) {
        float4 av = *(const float4*)(Arow + kt);
        float4 wv = *(const float4*)(Wrow + kt);
        __syncthreads();   // prior compute done reading LDS
        As[kq+0][lr] = av.x; As[kq+1][lr] = av.y;
        As[kq+2][lr] = av.z; As[kq+3][lr] = av.w;
        Bs[kq+0][lr] = wv.x; Bs[kq+1][lr] = wv.y;
        Bs[kq+2][lr] = wv.z; Bs[kq+3][lr] = wv.w;
        __syncthreads();
        #pragma unroll
        for (int kk = 0; kk < 16; ++kk) {
            float4 a4 = *(const float4*)&As[kk][ty*4];
            float4 b4 = *(const float4*)&Bs[kk][tx*4];
            float a[4] = {a4.x, a4.y, a4.z, a4.w};
            float b[4] = {b4.x, b4.y, b4.z, b4.w};
            #pragma unroll
            for (int i = 0; i < 4; ++i)
                #pragma unroll
                for (int j = 0; j < 4; ++j)
                    acc[i][j] = fmaf(a[i], b[j], acc[i][j]);
        }
    }

    float4 bb = make_float4(0.f, 0.f, 0.f, 0.f);
    if (bias) bb = *(const float4*)&bias[n0 + tx*4];
    #pragma unroll
    for (int i = 0; i < 4; ++i) {
        float4 r;
        r.x = acc[i][0] + bb.x;
        r.y = acc[i][1] + bb.y;
        r.z = acc[i][2] + bb.z;
        r.w = acc[i][3] + bb.w;
        *(float4*)&C[(size_t)(m0 + ty*4 + i) * Nc + n0 + tx*4] = r;
    }
}

// ---------------------------------------------------------------------------
// Flash-style attention (fp32, online softmax).
// Grid: B*H*(L/TL) blocks, 256 threads.
// q:   [B*L, HID]   (head h at cols h*64..h*64+63)
// kv:  [B*N, 2*HID] (k at cols h*64.., v at cols 512+h*64..)
// mask:[B,H,L,N]
// o:   [B*L, HID]
// ---------------------------------------------------------------------------
#define TL 32
#define TN 128

__global__ __launch_bounds__(256)
void attn_kernel(const float* __restrict__ q, const float* __restrict__ kv,
                 const float* __restrict__ mask, float* __restrict__ o)
{
    __shared__ float Qs[TL][65];        // [r][d], odd stride: <=4-way b32 conflicts
    __shared__ float KVs[TN][65];       // [n][d] for K, then reused for V
    __shared__ float Ss[TL][TN + 4];    // [r][c] logits -> probabilities
    __shared__ float red[TL][8];
    __shared__ float row_m[TL], row_l[TL], row_alpha[TL], row_mcur[TL];

    const int t   = threadIdx.x;
    const int nlt = L_ / TL;                  // 32
    const int lt  = blockIdx.x & (nlt - 1);
    const int h   = (blockIdx.x >> 5) & (H_ - 1);
    const int b   = blockIdx.x >> 8;
    const int l0  = lt * TL;

    // load Q tile (TL x 64)
    for (int g = t; g < TL * 16; g += 256) {
        int r = g >> 4, d4 = (g & 15) * 4;
        float4 v = *(const float4*)&q[(size_t)(b*L_ + l0 + r) * HID_ + h*HD_ + d4];
        Qs[r][d4+0] = v.x; Qs[r][d4+1] = v.y; Qs[r][d4+2] = v.z; Qs[r][d4+3] = v.w;
    }
    if (t < TL) { row_m[t] = -1e30f; row_l[t] = 0.f; }

    // O accumulator: ro = t/32 -> rows ro*4..+3 ; tco = t%32 -> dims tco, tco+32
    const int ro  = t >> 5;
    const int tco = t & 31;
    float Oacc[4][2] = {{0.f,0.f},{0.f,0.f},{0.f,0.f},{0.f,0.f}};

    const float* kbase = kv + (size_t)b * N_ * (2*HID_) + h*HD_;
    const float* vbase = kbase + HID_;
    const float* mbase = mask + ((size_t)(b*H_ + h) * L_ + l0) * N_;

    // S-compute mapping: rows (t>>5)*4.., cols (t&31)*4..
    const int sr0 = (t >> 5) * 4;
    const int sc0 = (t & 31) * 4;
    // stats mapping: 8 threads per row
    const int str = t >> 3;
    const int stj = t & 7;

    for (int nt = 0; nt < N_ / TN; ++nt) {
        const int n0 = nt * TN;
        __syncthreads();   // prior PV done with KVs/Ss
        // load K tile (TN x 64)
        for (int g = t; g < TN * 16; g += 256) {
            int n = g >> 4, d4 = (g & 15) * 4;
            float4 v = *(const float4*)&kbase[(size_t)(n0 + n) * (2*HID_) + d4];
            KVs[n][d4+0] = v.x; KVs[n][d4+1] = v.y;
            KVs[n][d4+2] = v.z; KVs[n][d4+3] = v.w;
        }
        __syncthreads();
        // S = scale * Q K^T + mask (4x4 per thread)
        {
            float acc[4][4] = {{0.f,0.f,0.f,0.f},{0.f,0.f,0.f,0.f},
                               {0.f,0.f,0.f,0.f},{0.f,0.f,0.f,0.f}};
            #pragma unroll 4
            for (int d = 0; d < HD_; ++d) {
                float qv[4], kvv[4];
                #pragma unroll
                for (int i = 0; i < 4; ++i) qv[i]  = Qs[sr0+i][d];
                #pragma unroll
                for (int j = 0; j < 4; ++j) kvv[j] = KVs[sc0+j][d];
                #pragma unroll
                for (int i = 0; i < 4; ++i)
                    #pragma unroll
                    for (int j = 0; j < 4; ++j)
                        acc[i][j] = fmaf(qv[i], kvv[j], acc[i][j]);
            }
            #pragma unroll
            for (int i = 0; i < 4; ++i) {
                float4 mk = *(const float4*)&mbase[(size_t)(sr0+i) * N_ + n0 + sc0];
                Ss[sr0+i][sc0+0] = fmaf(acc[i][0], SCALE_, mk.x);
                Ss[sr0+i][sc0+1] = fmaf(acc[i][1], SCALE_, mk.y);
                Ss[sr0+i][sc0+2] = fmaf(acc[i][2], SCALE_, mk.z);
                Ss[sr0+i][sc0+3] = fmaf(acc[i][3], SCALE_, mk.w);
            }
        }
        __syncthreads();
        // partial row max
        {
            float mx = -1e30f;
            #pragma unroll
            for (int c = 0; c < 16; ++c) mx = fmaxf(mx, Ss[str][stj*16 + c]);
            red[str][stj] = mx;
        }
        __syncthreads();
        if (t < TL) {
            float mx = red[t][0];
            #pragma unroll
            for (int j = 1; j < 8; ++j) mx = fmaxf(mx, red[t][j]);
            float mold = row_m[t];
            float mnew = fmaxf(mold, mx);
            row_m[t]     = mnew;
            row_alpha[t] = __expf(mold - mnew);   // 0 on first tile
            row_mcur[t]  = mnew;
        }
        __syncthreads();
        // exponentiate + partial row sum
        {
            float mnew = row_mcur[str];
            float s = 0.f;
            #pragma unroll
            for (int c = 0; c < 16; ++c) {
                float p = __expf(Ss[str][stj*16 + c] - mnew);
                Ss[str][stj*16 + c] = p;
                s += p;
            }
            red[str][stj] = s;
        }
        __syncthreads();
        if (t < TL) {
            float s = 0.f;
            #pragma unroll
            for (int j = 0; j < 8; ++j) s += red[t][j];
            row_l[t] = row_l[t] * row_alpha[t] + s;
        }
        // load V tile into KVs (K reads finished two syncs ago)
        for (int g = t; g < TN * 16; g += 256) {
            int n = g >> 4, d4 = (g & 15) * 4;
            float4 v = *(const float4*)&vbase[(size_t)(n0 + n) * (2*HID_) + d4];
            KVs[n][d4+0] = v.x; KVs[n][d4+1] = v.y;
            KVs[n][d4+2] = v.z; KVs[n][d4+3] = v.w;
        }
        __syncthreads();
        // O = O*alpha + P @ V
        {
            float al[4];
            #pragma unroll
            for (int i = 0; i < 4; ++i) al[i] = row_alpha[ro*4 + i];
            #pragma unroll
            for (int i = 0; i < 4; ++i) { Oacc[i][0] *= al[i]; Oacc[i][1] *= al[i]; }
            for (int c = 0; c < TN; ++c) {
                float v0 = KVs[c][tco];
                float v1 = KVs[c][tco + 32];
                #pragma unroll
                for (int i = 0; i < 4; ++i) {
                    float p = Ss[ro*4 + i][c];
                    Oacc[i][0] = fmaf(p, v0, Oacc[i][0]);
                    Oacc[i][1] = fmaf(p, v1, Oacc[i][1]);
                }
            }
        }
    }
    __syncthreads();
    // finalize: divide by row sum, write out
    #pragma unroll
    for (int i = 0; i < 4; ++i) {
        int r = ro*4 + i;
        float inv = 1.f / row_l[r];
        size_t base = (size_t)(b*L_ + l0 + r) * HID_ + h*HD_;
        o[base + tco]      = Oacc[i][0] * inv;
        o[base + tco + 32] = Oacc[i][1] * inv;
    }
}

// ---------------------------------------------------------------------------
extern "C" void kernel_launch(void* const* d_in, const int* in_sizes, int n_in,
                              void* d_out, int out_size, void* d_ws, size_t ws_size,
                              hipStream_t stream)
{
    const float* x      = (const float*)d_in[0];  // [B,L,VDIM]
    const float* vfeats = (const float*)d_in[1];  // [B,N,LDIM]
    const float* mask   = (const float*)d_in[2];  // [B,H,L,N]
    const float* Wq     = (const float*)d_in[3];  // [HID,VDIM]
    const float* Wkv    = (const float*)d_in[4];  // [2*HID,LDIM]
    const float* Wproj  = (const float*)d_in[5];  // [VDIM,HID]
    const float* bproj  = (const float*)d_in[6];  // [VDIM]
    float* out = (float*)d_out;                   // [B,L,VDIM]

    char* ws = (char*)d_ws;
    float* qbuf  = (float*)ws;                                    // 4096*512  (8 MB)
    float* kvbuf = (float*)(ws + (size_t)4096*512*4);             // 8192*1024 (32 MB)
    float* aobuf = (float*)(ws + (size_t)4096*512*4 + (size_t)8192*1024*4); // 8 MB

    dim3 blk(256);
    // q = x @ Wq^T : [4096,512]
    gemm_nt<<<dim3(VDIM_/64 /* Nc=512 */ , (B_*L_)/64), blk, 0, stream>>>(
        x, Wq, nullptr, qbuf, B_*L_, HID_, VDIM_);
    // kv = vfeats @ Wkv^T : [8192,1024]
    gemm_nt<<<dim3((2*HID_)/64, (B_*N_)/64), blk, 0, stream>>>(
        vfeats, Wkv, nullptr, kvbuf, B_*N_, 2*HID_, LDIM_);
    // attention
    attn_kernel<<<dim3(B_*H_*(L_/TL)), blk, 0, stream>>>(qbuf, kvbuf, mask, aobuf);
    // out = attn_out @ Wproj^T + bproj : [4096,512]
    gemm_nt<<<dim3(VDIM_/64, (B_*L_)/64), blk, 0, stream>>>(
        aobuf, Wproj, bproj, out, B_*L_, VDIM_, HID_);
}

// Round 3
// 482.908 us; speedup vs baseline: 2.0882x; 2.0882x over previous
//
#include <hip/hip_runtime.h>
#include <math.h>

// Problem constants
#define B_ 4
#define L_ 1024
#define N_ 2048
#define VDIM_ 512
#define LDIM_ 768
#define HID_ 512
#define H_ 8
#define HD_ 64
#define SCALE_ 0.125f

typedef __bf16 bf16;
typedef __bf16 bf16x4 __attribute__((ext_vector_type(4)));
typedef __bf16 bf16x8 __attribute__((ext_vector_type(8)));
typedef float f32x4 __attribute__((ext_vector_type(4)));

// Async global->LDS, 16B per lane. LDS dest = wave-uniform base + lane*16.
__device__ __forceinline__ void async_cp16(const bf16* g, bf16* l) {
    __builtin_amdgcn_global_load_lds(
        (const __attribute__((address_space(1))) unsigned int*)g,
        (__attribute__((address_space(3))) unsigned int*)l, 16, 0, 0);
}

// ---------------------------------------------------------------------------
// Elementwise converts
// ---------------------------------------------------------------------------
__global__ void cvt_bf16(const float* __restrict__ in, bf16* __restrict__ out, int n) {
    int i = (blockIdx.x * 256 + threadIdx.x) * 4;
    if (i < n) {
        float4 v = *(const float4*)(in + i);
        bf16x4 o;
        o[0] = (bf16)v.x; o[1] = (bf16)v.y; o[2] = (bf16)v.z; o[3] = (bf16)v.w;
        *(bf16x4*)(out + i) = o;
    }
}

__global__ void cvt_split(const float* __restrict__ in, bf16* __restrict__ hi,
                          bf16* __restrict__ lo, int n) {
    int i = (blockIdx.x * 256 + threadIdx.x) * 4;
    if (i < n) {
        float4 v = *(const float4*)(in + i);
        bf16x4 h, lw;
        float vv[4] = {v.x, v.y, v.z, v.w};
        #pragma unroll
        for (int j = 0; j < 4; ++j) {
            bf16 hb = (bf16)vv[j];
            h[j] = hb;
            lw[j] = (bf16)(vv[j] - (float)hb);
        }
        *(bf16x4*)(hi + i) = h;
        *(bf16x4*)(lo + i) = lw;
    }
}

// ---------------------------------------------------------------------------
// Plain bf16 MFMA GEMM: C[M,N](bf16) = A[M,K](bf16) @ W[N,K](bf16)^T
// BK=64. 4 waves in 2x2; wave tile (BM/2) x (BN/2). LDS chunk-XOR swizzle:
// chunk c (8 bf16) of row r stored at physical chunk c^(r&7) (8 chunks/row).
// ---------------------------------------------------------------------------
template<int BM, int BN>
__global__ __launch_bounds__(256)
void gemm_bf16(const bf16* __restrict__ A, const bf16* __restrict__ W,
               bf16* __restrict__ C, int M, int N, int K)
{
    __shared__ bf16 As[BM * 64];
    __shared__ bf16 Ws[BN * 64];
    const int t = threadIdx.x, l = t & 63, wv = t >> 6;
    const int n0 = blockIdx.x * BN, m0 = blockIdx.y * BM;
    const int wm = (wv >> 1) * (BM / 2), wn = (wv & 1) * (BN / 2);
    constexpr int TI = BM / 32, TJ = BN / 32;
    const int lq = l & 15, qd = l >> 4, swz = l & 7;

    f32x4 acc[TI][TJ];
    #pragma unroll
    for (int i = 0; i < TI; ++i)
        #pragma unroll
        for (int j = 0; j < TJ; ++j)
            #pragma unroll
            for (int r = 0; r < 4; ++r) acc[i][j][r] = 0.f;

    for (int kt = 0; kt < K; kt += 64) {
        __syncthreads();
        for (int it = wv; it < BM / 8; it += 4) {
            int r = it * 8 + (l >> 3);
            int c = (l & 7) ^ (r & 7);
            async_cp16(A + (size_t)(m0 + r) * K + kt + c * 8, &As[it * 512]);
        }
        for (int it = wv; it < BN / 8; it += 4) {
            int r = it * 8 + (l >> 3);
            int c = (l & 7) ^ (r & 7);
            async_cp16(W + (size_t)(n0 + r) * K + kt + c * 8, &Ws[it * 512]);
        }
        __syncthreads();
        #pragma unroll
        for (int ks = 0; ks < 2; ++ks) {
            bf16x8 af[TI], wf[TJ];
            #pragma unroll
            for (int i = 0; i < TI; ++i) {
                int row = wm + i * 16 + lq;
                af[i] = *(const bf16x8*)&As[row * 64 + (((ks * 4 + qd)) ^ swz) * 8];
            }
            #pragma unroll
            for (int j = 0; j < TJ; ++j) {
                int row = wn + j * 16 + lq;
                wf[j] = *(const bf16x8*)&Ws[row * 64 + (((ks * 4 + qd)) ^ swz) * 8];
            }
            #pragma unroll
            for (int i = 0; i < TI; ++i)
                #pragma unroll
                for (int j = 0; j < TJ; ++j)
                    acc[i][j] = __builtin_amdgcn_mfma_f32_16x16x32_bf16(
                        af[i], wf[j], acc[i][j], 0, 0, 0);
        }
    }
    #pragma unroll
    for (int i = 0; i < TI; ++i)
        #pragma unroll
        for (int j = 0; j < TJ; ++j)
            #pragma unroll
            for (int r = 0; r < 4; ++r) {
                int row = m0 + wm + i * 16 + qd * 4 + r;
                int col = n0 + wn + j * 16 + lq;
                C[(size_t)row * N + col] = (bf16)acc[i][j][r];
            }
}

// ---------------------------------------------------------------------------
// Split (3-term) GEMM for projection: fp32-accurate.
// Cf[M,N] = (Ah+Al)[M,K] @ (Wh+Wl)[N,K]^T + bias.  BM=64, BN=128, BK=64.
// ---------------------------------------------------------------------------
__global__ __launch_bounds__(256)
void gemm_proj_split(const bf16* __restrict__ Ah, const bf16* __restrict__ Al,
                     const bf16* __restrict__ Wh, const bf16* __restrict__ Wl,
                     const float* __restrict__ bias, float* __restrict__ Cf,
                     int M, int N, int K)
{
    __shared__ bf16 sAh[64 * 64], sAl[64 * 64];
    __shared__ bf16 sWh[128 * 64], sWl[128 * 64];
    const int t = threadIdx.x, l = t & 63, wv = t >> 6;
    const int n0 = blockIdx.x * 128, m0 = blockIdx.y * 64;
    const int wm = (wv >> 1) * 32, wn = (wv & 1) * 64;
    const int lq = l & 15, qd = l >> 4, swz = l & 7;

    f32x4 acc[2][4];
    #pragma unroll
    for (int i = 0; i < 2; ++i)
        #pragma unroll
        for (int j = 0; j < 4; ++j)
            #pragma unroll
            for (int r = 0; r < 4; ++r) acc[i][j][r] = 0.f;

    for (int kt = 0; kt < K; kt += 64) {
        __syncthreads();
        for (int it = wv; it < 8; it += 4) {
            int r = it * 8 + (l >> 3);
            int c = (l & 7) ^ (r & 7);
            size_t go = (size_t)(m0 + r) * K + kt + c * 8;
            async_cp16(Ah + go, &sAh[it * 512]);
            async_cp16(Al + go, &sAl[it * 512]);
        }
        for (int it = wv; it < 16; it += 4) {
            int r = it * 8 + (l >> 3);
            int c = (l & 7) ^ (r & 7);
            size_t go = (size_t)(n0 + r) * K + kt + c * 8;
            async_cp16(Wh + go, &sWh[it * 512]);
            async_cp16(Wl + go, &sWl[it * 512]);
        }
        __syncthreads();
        #pragma unroll
        for (int ks = 0; ks < 2; ++ks) {
            bf16x8 ah[2], al2[2], wh[4], wl[4];
            #pragma unroll
            for (int i = 0; i < 2; ++i) {
                int off = (wm + i * 16 + lq) * 64 + ((ks * 4 + qd) ^ swz) * 8;
                ah[i]  = *(const bf16x8*)&sAh[off];
                al2[i] = *(const bf16x8*)&sAl[off];
            }
            #pragma unroll
            for (int j = 0; j < 4; ++j) {
                int off = (wn + j * 16 + lq) * 64 + ((ks * 4 + qd) ^ swz) * 8;
                wh[j] = *(const bf16x8*)&sWh[off];
                wl[j] = *(const bf16x8*)&sWl[off];
            }
            #pragma unroll
            for (int i = 0; i < 2; ++i)
                #pragma unroll
                for (int j = 0; j < 4; ++j) {
                    acc[i][j] = __builtin_amdgcn_mfma_f32_16x16x32_bf16(ah[i],  wh[j], acc[i][j], 0, 0, 0);
                    acc[i][j] = __builtin_amdgcn_mfma_f32_16x16x32_bf16(ah[i],  wl[j], acc[i][j], 0, 0, 0);
                    acc[i][j] = __builtin_amdgcn_mfma_f32_16x16x32_bf16(al2[i], wh[j], acc[i][j], 0, 0, 0);
                }
        }
    }
    #pragma unroll
    for (int i = 0; i < 2; ++i)
        #pragma unroll
        for (int j = 0; j < 4; ++j) {
            int col = n0 + wn + j * 16 + lq;
            float bb = bias[col];
            #pragma unroll
            for (int r = 0; r < 4; ++r) {
                int row = m0 + wm + i * 16 + qd * 4 + r;
                Cf[(size_t)row * N + col] = acc[i][j][r] + bb;
            }
        }
}

// ---------------------------------------------------------------------------
// Transpose v-part of kv into vT[(b*H+h)*HD + d][n]  (bf16)
// Grid: 1024 blocks (b,h,ntile of 64), 256 threads.
// ---------------------------------------------------------------------------
__global__ __launch_bounds__(256)
void transpose_v(const bf16* __restrict__ kv, bf16* __restrict__ vT)
{
    __shared__ bf16 T[64 * 64];
    const int t = threadIdx.x;
    const int bid = blockIdx.x;
    const int nt = bid & 31, h = (bid >> 5) & 7, b = bid >> 8;
    const int n0 = nt * 64;
    for (int g = t; g < 512; g += 256) {
        int r = g >> 3, c = g & 7;
        bf16x8 v = *(const bf16x8*)(kv + (size_t)(b * N_ + n0 + r) * (2 * HID_) +
                                    HID_ + h * HD_ + c * 8);
        *(bf16x8*)&T[r * 64 + (c ^ (r & 7)) * 8] = v;
    }
    __syncthreads();
    for (int g = t; g < 512; g += 256) {
        int d = g >> 3, kg = g & 7;
        bf16x8 ov;
        #pragma unroll
        for (int jj = 0; jj < 8; ++jj) {
            int key = kg * 8 + jj;
            ov[jj] = T[key * 64 + (((d >> 3) ^ (key & 7))) * 8 + (d & 7)];
        }
        *(bf16x8*)&vT[(size_t)((b * H_ + h) * HD_ + d) * N_ + n0 + kg * 8] = ov;
    }
}

// ---------------------------------------------------------------------------
// Flash attention, bf16 MFMA. Block = 64 Q rows (4 waves x 16), KT=64 keys.
// Softmax state per-lane (16-lane shfl reductions). P via wave-private LDS.
// Output: attn_out split hi/lo bf16 for the split proj GEMM.
// ---------------------------------------------------------------------------
__global__ __launch_bounds__(256)
void attn_mfma(const bf16* __restrict__ q, const bf16* __restrict__ kv,
               const bf16* __restrict__ vT, const float* __restrict__ mask,
               bf16* __restrict__ ao_hi, bf16* __restrict__ ao_lo)
{
    __shared__ bf16 Ks[64 * 64];       // [key][dim], chunk-swizzled
    __shared__ bf16 Vs[64 * 64];       // [dim][key], chunk-swizzled
    __shared__ bf16 Pa[4][16 * 72];    // per-wave [qrow][key], stride 72
    const int t = threadIdx.x, l = t & 63, wv = t >> 6;
    const int bid = blockIdx.x;
    const int lt = bid & 15, h = (bid >> 4) & 7, b = bid >> 7;
    const int l0 = lt * 64;
    const int lq = l & 15, qd = l >> 4, swz = l & 7;

    // Q A-fragments (once): a[j] = Q[m=lq][k=qd*8+j] (+32 for ks=1)
    bf16x8 qf[2];
    {
        const bf16* qb = q + (size_t)(b * L_ + l0 + wv * 16 + lq) * HID_ + h * HD_ + qd * 8;
        qf[0] = *(const bf16x8*)qb;
        qf[1] = *(const bf16x8*)(qb + 32);
    }

    f32x4 o[4];
    #pragma unroll
    for (int j = 0; j < 4; ++j)
        #pragma unroll
        for (int r = 0; r < 4; ++r) o[j][r] = 0.f;
    float m_run[4], l_run[4];
    #pragma unroll
    for (int r = 0; r < 4; ++r) { m_run[r] = -1e30f; l_run[r] = 0.f; }

    const bf16* kb = kv + (size_t)(b * N_) * (2 * HID_) + h * HD_;
    const bf16* vb = vT + (size_t)((b * H_ + h) * HD_) * N_;
    const size_t mrow0 = (size_t)((b * H_ + h) * L_ + l0 + wv * 16);
    bf16* Paw = &Pa[wv][0];

    for (int nt = 0; nt < N_ / 64; ++nt) {
        const int n0 = nt * 64;
        __syncthreads();
        // mask loads (independent of LDS; in flight across staging barrier)
        float mk[4][4];
        #pragma unroll
        for (int jj = 0; jj < 4; ++jj)
            #pragma unroll
            for (int r = 0; r < 4; ++r)
                mk[jj][r] = mask[(mrow0 + qd * 4 + r) * N_ + n0 + jj * 16 + lq];
        // stage K tile and V^T tile
        for (int it = wv; it < 8; it += 4) {
            int r = it * 8 + (l >> 3);
            int c = (l & 7) ^ (r & 7);
            async_cp16(kb + (size_t)(n0 + r) * (2 * HID_) + c * 8, &Ks[it * 512]);
            async_cp16(vb + (size_t)r * N_ + n0 + c * 8, &Vs[it * 512]);
        }
        __syncthreads();
        // S = Q K^T
        f32x4 s[4];
        #pragma unroll
        for (int jj = 0; jj < 4; ++jj)
            #pragma unroll
            for (int r = 0; r < 4; ++r) s[jj][r] = 0.f;
        #pragma unroll
        for (int ks = 0; ks < 2; ++ks)
            #pragma unroll
            for (int jj = 0; jj < 4; ++jj) {
                bf16x8 kf = *(const bf16x8*)&Ks[(jj * 16 + lq) * 64 +
                                                ((ks * 4 + qd) ^ swz) * 8];
                s[jj] = __builtin_amdgcn_mfma_f32_16x16x32_bf16(qf[ks], kf, s[jj], 0, 0, 0);
            }
        // logits
        float sv[4][4];
        #pragma unroll
        for (int jj = 0; jj < 4; ++jj)
            #pragma unroll
            for (int r = 0; r < 4; ++r)
                sv[jj][r] = fmaf(s[jj][r], SCALE_, mk[jj][r]);
        // online softmax (rows = qd*4+r, reduce over the 16 lanes sharing qd)
        float alpha[4], mnew[4];
        #pragma unroll
        for (int r = 0; r < 4; ++r) {
            float mx = fmaxf(fmaxf(sv[0][r], sv[1][r]), fmaxf(sv[2][r], sv[3][r]));
            #pragma unroll
            for (int d2 = 1; d2 < 16; d2 <<= 1) mx = fmaxf(mx, __shfl_xor(mx, d2));
            mnew[r] = fmaxf(m_run[r], mx);
            alpha[r] = __expf(m_run[r] - mnew[r]);
            m_run[r] = mnew[r];
        }
        bf16 pb[4][4];
        #pragma unroll
        for (int r = 0; r < 4; ++r) {
            float ss = 0.f;
            #pragma unroll
            for (int jj = 0; jj < 4; ++jj) {
                float p = __expf(sv[jj][r] - mnew[r]);
                pb[jj][r] = (bf16)p;
                ss += p;
            }
            #pragma unroll
            for (int d2 = 1; d2 < 16; d2 <<= 1) ss += __shfl_xor(ss, d2);
            l_run[r] = l_run[r] * alpha[r] + ss;
        }
        // P -> wave-private LDS (C-layout write, A-layout read)
        #pragma unroll
        for (int jj = 0; jj < 4; ++jj)
            #pragma unroll
            for (int r = 0; r < 4; ++r)
                Paw[(qd * 4 + r) * 72 + jj * 16 + lq] = pb[jj][r];
        __asm__ __volatile__("s_waitcnt lgkmcnt(0)" ::: "memory");
        // O = O*alpha + P V
        #pragma unroll
        for (int jj = 0; jj < 4; ++jj)
            #pragma unroll
            for (int r = 0; r < 4; ++r) o[jj][r] *= alpha[r];
        #pragma unroll
        for (int ks = 0; ks < 2; ++ks) {
            bf16x8 pf = *(const bf16x8*)&Paw[lq * 72 + ks * 32 + qd * 8];
            #pragma unroll
            for (int jj = 0; jj < 4; ++jj) {
                bf16x8 vf = *(const bf16x8*)&Vs[(jj * 16 + lq) * 64 +
                                                ((ks * 4 + qd) ^ swz) * 8];
                o[jj] = __builtin_amdgcn_mfma_f32_16x16x32_bf16(pf, vf, o[jj], 0, 0, 0);
            }
        }
    }
    // epilogue: normalize + split hi/lo
    #pragma unroll
    for (int jj = 0; jj < 4; ++jj)
        #pragma unroll
        for (int r = 0; r < 4; ++r) {
            int row = b * L_ + l0 + wv * 16 + qd * 4 + r;
            int col = h * HD_ + jj * 16 + lq;
            float v = o[jj][r] / l_run[r];
            bf16 hb = (bf16)v;
            ao_hi[(size_t)row * HID_ + col] = hb;
            ao_lo[(size_t)row * HID_ + col] = (bf16)(v - (float)hb);
        }
}

// ---------------------------------------------------------------------------
extern "C" void kernel_launch(void* const* d_in, const int* in_sizes, int n_in,
                              void* d_out, int out_size, void* d_ws, size_t ws_size,
                              hipStream_t stream)
{
    const float* x      = (const float*)d_in[0];  // [B,L,VDIM]
    const float* vfeats = (const float*)d_in[1];  // [B,N,LDIM]
    const float* mask   = (const float*)d_in[2];  // [B,H,L,N]
    const float* Wq     = (const float*)d_in[3];  // [HID,VDIM]
    const float* Wkv    = (const float*)d_in[4];  // [2*HID,LDIM]
    const float* Wproj  = (const float*)d_in[5];  // [VDIM,HID]
    const float* bproj  = (const float*)d_in[6];  // [VDIM]
    float* out = (float*)d_out;                   // [B,L,VDIM] fp32

    // Workspace layout (45.1 MB; buffers aliased across dead ranges)
    char* ws = (char*)d_ws;
    bf16* vfb = (bf16*)(ws);                      // 12.58 MB (dead after kv GEMM)
    bf16* vTb = (bf16*)(ws);                      // 8.39 MB  (aliases vfb)
    bf16* kvb = (bf16*)(ws + 12582912);           // 16.78 MB
    bf16* xb  = (bf16*)(ws + 29360128);           // 4.19 MB  (dead after q GEMM)
    bf16* aoh = (bf16*)(ws + 29360128);           // aliases xb
    bf16* qb  = (bf16*)(ws + 33554432);           // 4.19 MB
    bf16* aol = (bf16*)(ws + 37748736);           // 4.19 MB
    bf16* wqb = (bf16*)(ws + 41943040);           // 0.52 MB
    bf16* wkvb= (bf16*)(ws + 42467328);           // 1.57 MB
    bf16* wph = (bf16*)(ws + 44040192);           // 0.52 MB
    bf16* wpl = (bf16*)(ws + 44564480);           // 0.52 MB

    dim3 blk(256);
    // converts
    cvt_bf16<<<dim3(B_*L_*VDIM_/1024),   blk, 0, stream>>>(x,      xb,   B_*L_*VDIM_);
    cvt_bf16<<<dim3(B_*N_*LDIM_/1024),   blk, 0, stream>>>(vfeats, vfb,  B_*N_*LDIM_);
    cvt_bf16<<<dim3(HID_*VDIM_/1024),    blk, 0, stream>>>(Wq,     wqb,  HID_*VDIM_);
    cvt_bf16<<<dim3(2*HID_*LDIM_/1024),  blk, 0, stream>>>(Wkv,    wkvb, 2*HID_*LDIM_);
    cvt_split<<<dim3(VDIM_*HID_/1024),   blk, 0, stream>>>(Wproj,  wph, wpl, VDIM_*HID_);
    // q = x @ Wq^T : [4096,512]
    gemm_bf16<64,128><<<dim3(HID_/128, B_*L_/64), blk, 0, stream>>>(
        xb, wqb, qb, B_*L_, HID_, VDIM_);
    // kv = vfeats @ Wkv^T : [8192,1024]
    gemm_bf16<128,128><<<dim3(2*HID_/128, B_*N_/128), blk, 0, stream>>>(
        vfb, wkvb, kvb, B_*N_, 2*HID_, LDIM_);
    // v-part -> vT[(b,h,d)][n]
    transpose_v<<<dim3(B_*H_*(N_/64)), blk, 0, stream>>>(kvb, vTb);
    // attention
    attn_mfma<<<dim3(B_*H_*(L_/64)), blk, 0, stream>>>(qb, kvb, vTb, mask, aoh, aol);
    // out = attn_out @ Wproj^T + bproj (split, fp32-accurate)
    gemm_proj_split<<<dim3(VDIM_/128, B_*L_/64), blk, 0, stream>>>(
        aoh, aol, wph, wpl, bproj, out, B_*L_, VDIM_, HID_);
}

// Round 4
// 452.460 us; speedup vs baseline: 2.2288x; 1.0673x over previous
//
#include <hip/hip_runtime.h>
#include <math.h>

// Problem constants
#define B_ 4
#define L_ 1024
#define N_ 2048
#define VDIM_ 512
#define LDIM_ 768
#define HID_ 512
#define H_ 8
#define HD_ 64
#define SCALE_ 0.125f

typedef __bf16 bf16;
typedef __bf16 bf16x4 __attribute__((ext_vector_type(4)));
typedef __bf16 bf16x8 __attribute__((ext_vector_type(8)));
typedef float f32x4 __attribute__((ext_vector_type(4)));

// Async global->LDS, 16B per lane. LDS dest = wave-uniform base + lane*16.
__device__ __forceinline__ void async_cp16(const bf16* g, bf16* l) {
    __builtin_amdgcn_global_load_lds(
        (const __attribute__((address_space(1))) unsigned int*)g,
        (__attribute__((address_space(3))) unsigned int*)l, 16, 0, 0);
}

// ---------------------------------------------------------------------------
// Fused converts: x, vfeats, Wq, Wkv -> bf16 in one launch.
// Ranges are block-aligned (1024 elems/block) so branches are block-uniform.
// ---------------------------------------------------------------------------
#define XE_   2097152   // B*L*VDIM
#define VFE_  6291456   // B*N*LDIM
#define WQE_  262144    // HID*VDIM
#define WKVE_ 786432    // 2*HID*LDIM
__global__ void cvt_all(const float* __restrict__ x, const float* __restrict__ vf,
                        const float* __restrict__ wq, const float* __restrict__ wkv,
                        bf16* __restrict__ xb, bf16* __restrict__ vfb,
                        bf16* __restrict__ wqb, bf16* __restrict__ wkvb)
{
    int e = (blockIdx.x * 256 + threadIdx.x) * 4;
    const float* src; bf16* dst; int off;
    if (e < XE_)                        { src = x;   dst = xb;   off = 0; }
    else if (e < XE_ + VFE_)            { src = vf;  dst = vfb;  off = XE_; }
    else if (e < XE_ + VFE_ + WQE_)     { src = wq;  dst = wqb;  off = XE_ + VFE_; }
    else                                { src = wkv; dst = wkvb; off = XE_ + VFE_ + WQE_; }
    int i = e - off;
    float4 v = *(const float4*)(src + i);
    bf16x4 o;
    o[0] = (bf16)v.x; o[1] = (bf16)v.y; o[2] = (bf16)v.z; o[3] = (bf16)v.w;
    *(bf16x4*)(dst + i) = o;
}

__global__ void cvt_split(const float* __restrict__ in, bf16* __restrict__ hi,
                          bf16* __restrict__ lo, int n) {
    int i = (blockIdx.x * 256 + threadIdx.x) * 4;
    if (i < n) {
        float4 v = *(const float4*)(in + i);
        bf16x4 h, lw;
        float vv[4] = {v.x, v.y, v.z, v.w};
        #pragma unroll
        for (int j = 0; j < 4; ++j) {
            bf16 hb = (bf16)vv[j];
            h[j] = hb;
            lw[j] = (bf16)(vv[j] - (float)hb);
        }
        *(bf16x4*)(hi + i) = h;
        *(bf16x4*)(lo + i) = lw;
    }
}

// ---------------------------------------------------------------------------
// Plain bf16 MFMA GEMM: C[M,N](bf16) = A[M,K](bf16) @ W[N,K](bf16)^T
// BK=64. 4 waves in 2x2; wave tile (BM/2) x (BN/2). LDS chunk-XOR swizzle.
// ---------------------------------------------------------------------------
template<int BM, int BN>
__global__ __launch_bounds__(256)
void gemm_bf16(const bf16* __restrict__ A, const bf16* __restrict__ W,
               bf16* __restrict__ C, int M, int N, int K)
{
    __shared__ bf16 As[BM * 64];
    __shared__ bf16 Ws[BN * 64];
    const int t = threadIdx.x, l = t & 63, wv = t >> 6;
    const int n0 = blockIdx.x * BN, m0 = blockIdx.y * BM;
    const int wm = (wv >> 1) * (BM / 2), wn = (wv & 1) * (BN / 2);
    constexpr int TI = BM / 32, TJ = BN / 32;
    const int lq = l & 15, qd = l >> 4, swz = l & 7;

    f32x4 acc[TI][TJ];
    #pragma unroll
    for (int i = 0; i < TI; ++i)
        #pragma unroll
        for (int j = 0; j < TJ; ++j)
            #pragma unroll
            for (int r = 0; r < 4; ++r) acc[i][j][r] = 0.f;

    for (int kt = 0; kt < K; kt += 64) {
        __syncthreads();
        for (int it = wv; it < BM / 8; it += 4) {
            int r = it * 8 + (l >> 3);
            int c = (l & 7) ^ (r & 7);
            async_cp16(A + (size_t)(m0 + r) * K + kt + c * 8, &As[it * 512]);
        }
        for (int it = wv; it < BN / 8; it += 4) {
            int r = it * 8 + (l >> 3);
            int c = (l & 7) ^ (r & 7);
            async_cp16(W + (size_t)(n0 + r) * K + kt + c * 8, &Ws[it * 512]);
        }
        __syncthreads();
        #pragma unroll
        for (int ks = 0; ks < 2; ++ks) {
            bf16x8 af[TI], wf[TJ];
            #pragma unroll
            for (int i = 0; i < TI; ++i) {
                int row = wm + i * 16 + lq;
                af[i] = *(const bf16x8*)&As[row * 64 + ((ks * 4 + qd) ^ swz) * 8];
            }
            #pragma unroll
            for (int j = 0; j < TJ; ++j) {
                int row = wn + j * 16 + lq;
                wf[j] = *(const bf16x8*)&Ws[row * 64 + ((ks * 4 + qd) ^ swz) * 8];
            }
            #pragma unroll
            for (int i = 0; i < TI; ++i)
                #pragma unroll
                for (int j = 0; j < TJ; ++j)
                    acc[i][j] = __builtin_amdgcn_mfma_f32_16x16x32_bf16(
                        af[i], wf[j], acc[i][j], 0, 0, 0);
        }
    }
    #pragma unroll
    for (int i = 0; i < TI; ++i)
        #pragma unroll
        for (int j = 0; j < TJ; ++j)
            #pragma unroll
            for (int r = 0; r < 4; ++r) {
                int row = m0 + wm + i * 16 + qd * 4 + r;
                int col = n0 + wn + j * 16 + lq;
                C[(size_t)row * N + col] = (bf16)acc[i][j][r];
            }
}

// ---------------------------------------------------------------------------
// Projection GEMM (2-term split weights): Cf = A @ (Wh+Wl)^T + bias, fp32 out.
// BM=64, BN=64, BK=64. Grid 8x64 = 512 blocks.
// ---------------------------------------------------------------------------
__global__ __launch_bounds__(256)
void gemm_proj(const bf16* __restrict__ A, const bf16* __restrict__ Wh,
               const bf16* __restrict__ Wl, const float* __restrict__ bias,
               float* __restrict__ Cf, int M, int N, int K)
{
    __shared__ bf16 sA[64 * 64];
    __shared__ bf16 sWh[64 * 64], sWl[64 * 64];
    const int t = threadIdx.x, l = t & 63, wv = t >> 6;
    const int n0 = blockIdx.x * 64, m0 = blockIdx.y * 64;
    const int wm = (wv >> 1) * 32, wn = (wv & 1) * 32;
    const int lq = l & 15, qd = l >> 4, swz = l & 7;

    f32x4 acc[2][2];
    #pragma unroll
    for (int i = 0; i < 2; ++i)
        #pragma unroll
        for (int j = 0; j < 2; ++j)
            #pragma unroll
            for (int r = 0; r < 4; ++r) acc[i][j][r] = 0.f;

    for (int kt = 0; kt < K; kt += 64) {
        __syncthreads();
        for (int it = wv; it < 8; it += 4) {
            int r = it * 8 + (l >> 3);
            int c = (l & 7) ^ (r & 7);
            async_cp16(A  + (size_t)(m0 + r) * K + kt + c * 8, &sA[it * 512]);
            size_t go = (size_t)(n0 + r) * K + kt + c * 8;
            async_cp16(Wh + go, &sWh[it * 512]);
            async_cp16(Wl + go, &sWl[it * 512]);
        }
        __syncthreads();
        #pragma unroll
        for (int ks = 0; ks < 2; ++ks) {
            bf16x8 af[2], wh[2], wl[2];
            #pragma unroll
            for (int i = 0; i < 2; ++i) {
                int off = (wm + i * 16 + lq) * 64 + ((ks * 4 + qd) ^ swz) * 8;
                af[i] = *(const bf16x8*)&sA[off];
            }
            #pragma unroll
            for (int j = 0; j < 2; ++j) {
                int off = (wn + j * 16 + lq) * 64 + ((ks * 4 + qd) ^ swz) * 8;
                wh[j] = *(const bf16x8*)&sWh[off];
                wl[j] = *(const bf16x8*)&sWl[off];
            }
            #pragma unroll
            for (int i = 0; i < 2; ++i)
                #pragma unroll
                for (int j = 0; j < 2; ++j) {
                    acc[i][j] = __builtin_amdgcn_mfma_f32_16x16x32_bf16(af[i], wh[j], acc[i][j], 0, 0, 0);
                    acc[i][j] = __builtin_amdgcn_mfma_f32_16x16x32_bf16(af[i], wl[j], acc[i][j], 0, 0, 0);
                }
        }
    }
    #pragma unroll
    for (int i = 0; i < 2; ++i)
        #pragma unroll
        for (int j = 0; j < 2; ++j) {
            int col = n0 + wn + j * 16 + lq;
            float bb = bias[col];
            #pragma unroll
            for (int r = 0; r < 4; ++r) {
                int row = m0 + wm + i * 16 + qd * 4 + r;
                Cf[(size_t)row * N + col] = acc[i][j][r] + bb;
            }
        }
}

// ---------------------------------------------------------------------------
// Transpose v-part of kv into vT[(b*H+h)*HD + d][n]  (bf16)
// ---------------------------------------------------------------------------
__global__ __launch_bounds__(256)
void transpose_v(const bf16* __restrict__ kv, bf16* __restrict__ vT)
{
    __shared__ bf16 T[64 * 64];
    const int t = threadIdx.x;
    const int bid = blockIdx.x;
    const int nt = bid & 31, h = (bid >> 5) & 7, b = bid >> 8;
    const int n0 = nt * 64;
    for (int g = t; g < 512; g += 256) {
        int r = g >> 3, c = g & 7;
        bf16x8 v = *(const bf16x8*)(kv + (size_t)(b * N_ + n0 + r) * (2 * HID_) +
                                    HID_ + h * HD_ + c * 8);
        *(bf16x8*)&T[r * 64 + (c ^ (r & 7)) * 8] = v;
    }
    __syncthreads();
    for (int g = t; g < 512; g += 256) {
        int d = g >> 3, kg = g & 7;
        bf16x8 ov;
        #pragma unroll
        for (int jj = 0; jj < 8; ++jj) {
            int key = kg * 8 + jj;
            ov[jj] = T[key * 64 + (((d >> 3) ^ (key & 7))) * 8 + (d & 7)];
        }
        *(bf16x8*)&vT[(size_t)((b * H_ + h) * HD_ + d) * N_ + n0 + kg * 8] = ov;
    }
}

// ---------------------------------------------------------------------------
// Flash attention, bf16 MFMA. Block = 64 Q rows (4 waves x 16), KT=128 keys.
// Softmax state per-lane (16-lane shfl reductions). P via wave-private LDS.
// Output: attn_out plain bf16.
// ---------------------------------------------------------------------------
#define PST 136   // P LDS row stride (bf16)
__global__ __launch_bounds__(256)
void attn_mfma(const bf16* __restrict__ q, const bf16* __restrict__ kv,
               const bf16* __restrict__ vT, const float* __restrict__ mask,
               bf16* __restrict__ ao)
{
    __shared__ bf16 Ks[128 * 64];      // [key][dim], 8-chunk XOR swizzle (16 KB)
    __shared__ bf16 Vs[64 * 128];      // [dim][key], 16-chunk XOR swizzle (16 KB)
    __shared__ bf16 Pa[4][16 * PST];   // per-wave P [qrow][key] (17.4 KB)
    const int t = threadIdx.x, l = t & 63, wv = t >> 6;
    const int bid = blockIdx.x;
    const int lt = bid & 15, h = (bid >> 4) & 7, b = bid >> 7;
    const int l0 = lt * 64;
    const int lq = l & 15, qd = l >> 4, swz = l & 7;

    // Q A-fragments (held in regs for all iterations)
    bf16x8 qf[2];
    {
        const bf16* qb = q + (size_t)(b * L_ + l0 + wv * 16 + lq) * HID_ + h * HD_ + qd * 8;
        qf[0] = *(const bf16x8*)qb;
        qf[1] = *(const bf16x8*)(qb + 32);
    }

    f32x4 o[4];
    #pragma unroll
    for (int j = 0; j < 4; ++j)
        #pragma unroll
        for (int r = 0; r < 4; ++r) o[j][r] = 0.f;
    float m_run[4], l_run[4];
    #pragma unroll
    for (int r = 0; r < 4; ++r) { m_run[r] = -1e30f; l_run[r] = 0.f; }

    const bf16* kb = kv + (size_t)(b * N_) * (2 * HID_) + h * HD_;
    const bf16* vb = vT + (size_t)((b * H_ + h) * HD_) * N_;
    const size_t mrow0 = (size_t)((b * H_ + h) * L_ + l0 + wv * 16);
    bf16* Paw = &Pa[wv][0];

    for (int nt = 0; nt < N_ / 128; ++nt) {
        const int n0 = nt * 128;
        __syncthreads();   // prior iter done with LDS
        // mask loads first: in flight across the staging barrier
        float mk[8][4];
        #pragma unroll
        for (int jj = 0; jj < 8; ++jj)
            #pragma unroll
            for (int r = 0; r < 4; ++r)
                mk[jj][r] = mask[(mrow0 + qd * 4 + r) * N_ + n0 + jj * 16 + lq];
        // stage K (128 rows x 64 dims) and V^T (64 dims x 128 keys)
        for (int it = wv; it < 16; it += 4) {
            int r = it * 8 + (l >> 3);
            int c = (l & 7) ^ (r & 7);
            async_cp16(kb + (size_t)(n0 + r) * (2 * HID_) + c * 8, &Ks[it * 512]);
        }
        for (int it = wv; it < 16; it += 4) {
            int r = it * 4 + (l >> 4);
            int c = (l & 15) ^ (r & 15);
            async_cp16(vb + (size_t)r * N_ + n0 + c * 8, &Vs[it * 512]);
        }
        __syncthreads();
        // S = Q K^T  (16 MFMA)
        f32x4 s[8];
        #pragma unroll
        for (int jj = 0; jj < 8; ++jj)
            #pragma unroll
            for (int r = 0; r < 4; ++r) s[jj][r] = 0.f;
        #pragma unroll
        for (int ks = 0; ks < 2; ++ks)
            #pragma unroll
            for (int jj = 0; jj < 8; ++jj) {
                bf16x8 kf = *(const bf16x8*)&Ks[(jj * 16 + lq) * 64 +
                                                ((ks * 4 + qd) ^ swz) * 8];
                s[jj] = __builtin_amdgcn_mfma_f32_16x16x32_bf16(qf[ks], kf, s[jj], 0, 0, 0);
            }
        // logits (in place)
        #pragma unroll
        for (int jj = 0; jj < 8; ++jj)
            #pragma unroll
            for (int r = 0; r < 4; ++r)
                s[jj][r] = fmaf(s[jj][r], SCALE_, mk[jj][r]);
        // online softmax (row = qd*4+r; reduce over 16 lanes sharing qd)
        float alpha[4], mnew[4];
        #pragma unroll
        for (int r = 0; r < 4; ++r) {
            float mx = s[0][r];
            #pragma unroll
            for (int jj = 1; jj < 8; ++jj) mx = fmaxf(mx, s[jj][r]);
            #pragma unroll
            for (int d2 = 1; d2 < 16; d2 <<= 1) mx = fmaxf(mx, __shfl_xor(mx, d2));
            mnew[r] = fmaxf(m_run[r], mx);
            alpha[r] = __expf(m_run[r] - mnew[r]);
            m_run[r] = mnew[r];
        }
        bf16 pb[8][4];
        #pragma unroll
        for (int r = 0; r < 4; ++r) {
            float ss = 0.f;
            #pragma unroll
            for (int jj = 0; jj < 8; ++jj) {
                float p = __expf(s[jj][r] - mnew[r]);
                pb[jj][r] = (bf16)p;
                ss += p;
            }
            #pragma unroll
            for (int d2 = 1; d2 < 16; d2 <<= 1) ss += __shfl_xor(ss, d2);
            l_run[r] = l_run[r] * alpha[r] + ss;
        }
        // P -> wave-private LDS (C-layout write, A-layout read)
        #pragma unroll
        for (int jj = 0; jj < 8; ++jj)
            #pragma unroll
            for (int r = 0; r < 4; ++r)
                Paw[(qd * 4 + r) * PST + jj * 16 + lq] = pb[jj][r];
        __asm__ __volatile__("s_waitcnt lgkmcnt(0)" ::: "memory");
        // O = O*alpha + P V  (16 MFMA)
        #pragma unroll
        for (int jj = 0; jj < 4; ++jj)
            #pragma unroll
            for (int r = 0; r < 4; ++r) o[jj][r] *= alpha[r];
        #pragma unroll
        for (int ks = 0; ks < 4; ++ks) {
            bf16x8 pf = *(const bf16x8*)&Paw[lq * PST + ks * 32 + qd * 8];
            #pragma unroll
            for (int jj = 0; jj < 4; ++jj) {
                int d = jj * 16 + lq;
                bf16x8 vf = *(const bf16x8*)&Vs[d * 128 +
                                                ((ks * 4 + qd) ^ (d & 15)) * 8];
                o[jj] = __builtin_amdgcn_mfma_f32_16x16x32_bf16(pf, vf, o[jj], 0, 0, 0);
            }
        }
    }
    // epilogue: normalize + plain bf16 store
    #pragma unroll
    for (int jj = 0; jj < 4; ++jj)
        #pragma unroll
        for (int r = 0; r < 4; ++r) {
            int row = b * L_ + l0 + wv * 16 + qd * 4 + r;
            int col = h * HD_ + jj * 16 + lq;
            ao[(size_t)row * HID_ + col] = (bf16)(o[jj][r] / l_run[r]);
        }
}

// ---------------------------------------------------------------------------
extern "C" void kernel_launch(void* const* d_in, const int* in_sizes, int n_in,
                              void* d_out, int out_size, void* d_ws, size_t ws_size,
                              hipStream_t stream)
{
    const float* x      = (const float*)d_in[0];  // [B,L,VDIM]
    const float* vfeats = (const float*)d_in[1];  // [B,N,LDIM]
    const float* mask   = (const float*)d_in[2];  // [B,H,L,N]
    const float* Wq     = (const float*)d_in[3];  // [HID,VDIM]
    const float* Wkv    = (const float*)d_in[4];  // [2*HID,LDIM]
    const float* Wproj  = (const float*)d_in[5];  // [VDIM,HID]
    const float* bproj  = (const float*)d_in[6];  // [VDIM]
    float* out = (float*)d_out;                   // [B,L,VDIM] fp32

    // Workspace layout (~53.5 MB, no aliasing)
    char* ws = (char*)d_ws;
    bf16* xb   = (bf16*)(ws);                     // 4 MB
    bf16* vfb  = (bf16*)(ws + 4194304);           // 12 MB
    bf16* wqb  = (bf16*)(ws + 16777216);          // 0.5 MB
    bf16* wkvb = (bf16*)(ws + 17301504);          // 1.5 MB
    bf16* wph  = (bf16*)(ws + 18874368);          // 0.5 MB
    bf16* wpl  = (bf16*)(ws + 19398656);          // 0.5 MB
    bf16* qb   = (bf16*)(ws + 19922944);          // 4 MB
    bf16* kvb  = (bf16*)(ws + 24117248);          // 16 MB
    bf16* vTb  = (bf16*)(ws + 40894464);          // 8 MB
    bf16* aob  = (bf16*)(ws + 49283072);          // 4 MB

    dim3 blk(256);
    // converts (2 launches)
    cvt_all<<<dim3((XE_ + VFE_ + WQE_ + WKVE_) / 1024), blk, 0, stream>>>(
        x, vfeats, Wq, Wkv, xb, vfb, wqb, wkvb);
    cvt_split<<<dim3(VDIM_ * HID_ / 1024), blk, 0, stream>>>(Wproj, wph, wpl, VDIM_ * HID_);
    // q = x @ Wq^T : [4096,512]   grid 8x64 = 512 blocks
    gemm_bf16<64, 64><<<dim3(HID_ / 64, B_ * L_ / 64), blk, 0, stream>>>(
        xb, wqb, qb, B_ * L_, HID_, VDIM_);
    // kv = vfeats @ Wkv^T : [8192,1024]   grid 16x64 = 1024 blocks
    gemm_bf16<128, 64><<<dim3(2 * HID_ / 64, B_ * N_ / 128), blk, 0, stream>>>(
        vfb, wkvb, kvb, B_ * N_, 2 * HID_, LDIM_);
    // v-part -> vT[(b,h,d)][n]
    transpose_v<<<dim3(B_ * H_ * (N_ / 64)), blk, 0, stream>>>(kvb, vTb);
    // attention (512 blocks)
    attn_mfma<<<dim3(B_ * H_ * (L_ / 64)), blk, 0, stream>>>(qb, kvb, vTb, mask, aob);
    // out = attn_out @ (Wproj hi+lo)^T + bproj   grid 8x64 = 512 blocks
    gemm_proj<<<dim3(VDIM_ / 64, B_ * L_ / 64), blk, 0, stream>>>(
        aob, wph, wpl, bproj, out, B_ * L_, VDIM_, HID_);
}